// Round 1
// baseline (168.532 us; speedup 1.0000x reference)
//
#include <hip/hip_runtime.h>
#include <hip/hip_bf16.h>

#define CIN 128
#define COUT 256
#define H 56
#define W 56
#define OH 54
#define OW 54

#define CSTR 136   // LDS ci stride (bf16 elems): 272B -> odd 16B-granule stride
#define IWP 66     // iw dim incl. zero pad so (nr*16+15+kw) reads stay in-bounds

typedef __attribute__((ext_vector_type(8))) short short8;
typedef __attribute__((ext_vector_type(4))) float floatx4;

static __device__ __forceinline__ unsigned short f2bf(float f) {
  unsigned int u = __builtin_bit_cast(unsigned int, f);
  u += 0x7fffu + ((u >> 16) & 1u);   // RNE
  return (unsigned short)(u >> 16);
}

// w[co][ci][kh][kw] f32  ->  w2[kh][kw][c8][co][j] bf16   (ci = c8*8 + j)
__global__ void repack_w(const float* __restrict__ w, unsigned short* __restrict__ w2) {
  int idx = blockIdx.x * 256 + threadIdx.x;
  if (idx >= COUT * CIN * 9) return;
  int kw = idx % 3, t1 = idx / 3;
  int kh = t1 % 3, t2 = t1 / 3;
  int ci = t2 % CIN;
  int co = t2 / CIN;
  int c8 = ci >> 3, j = ci & 7;
  w2[((((kh * 3 + kw) * 16 + c8) * COUT + co) * 8) + j] = f2bf(w[idx]);
}

__global__ __launch_bounds__(256, 2) void conv_mfma(
    const float* __restrict__ x, const unsigned short* __restrict__ w2,
    const float* __restrict__ bias, float* __restrict__ out) {
  __shared__ alignas(16) unsigned short xs[4 * IWP * CSTR];  // 71,808 B

  const int ohp = blockIdx.x;   // 0..26  (output row pair)
  const int cb  = blockIdx.y;   // 0..3   (64-cout block)
  const int n   = blockIdx.z;   // 0..31
  const int oh0 = ohp * 2;
  const int tid = threadIdx.x;

  // ---- zero the iw pad region [56,66) ----
  for (int i = tid; i < 4 * 10 * CSTR; i += 256) {
    int r = i / (10 * CSTR);
    int rem = i % (10 * CSTR);
    int iw = 56 + rem / CSTR;
    int c = rem % CSTR;
    xs[(r * IWP + iw) * CSTR + c] = 0;
  }

  // ---- stage x rows: f32 global -> bf16 LDS, transposed to [row][iw][ci] ----
  {
    int iw = tid % 56;
    int r = tid / 56;           // 0..4; r==4 -> idle (tids 224..255)
    if (r < 4) {
      const float* xp = x + (size_t)n * CIN * (H * W) + (oh0 + r) * W + iw;
      unsigned short* xd = &xs[(r * IWP + iw) * CSTR];
      for (int c8 = 0; c8 < 16; ++c8) {
        short8 v;
        #pragma unroll
        for (int j = 0; j < 8; ++j)
          v[j] = (short)f2bf(xp[(size_t)(c8 * 8 + j) * (H * W)]);
        *reinterpret_cast<short8*>(&xd[c8 * 8]) = v;   // ds_write_b128
      }
    }
  }
  __syncthreads();

  // ---- wave decomposition: 4 waves = 2 co-halves x 2 output rows ----
  const int wid  = tid >> 6;
  const int lane = tid & 63;
  const int wm   = wid >> 1;       // co half (0/1)
  const int wn   = wid & 1;        // which output row of the pair
  const int l16  = lane & 15;
  const int cig  = lane >> 4;      // 0..3

  const int co_base = cb * 64 + wm * 32;
  const int oh = oh0 + wn;

  floatx4 acc[2][4];
  #pragma unroll
  for (int m = 0; m < 2; ++m)
    #pragma unroll
    for (int nr = 0; nr < 4; ++nr)
      acc[m][nr] = (floatx4){0.f, 0.f, 0.f, 0.f};

  for (int kh = 0; kh < 3; ++kh) {
    const int row = wn + kh;       // 0..3
    #pragma unroll
    for (int ch = 0; ch < 4; ++ch) {
      const int bbase = (row * IWP + l16) * CSTR + ch * 32 + cig * 8;
      #pragma unroll
      for (int kw = 0; kw < 3; ++kw) {
        // A fragments: direct from global (L2-resident repacked weights)
        const unsigned short* wp =
            w2 + ((size_t)(((kh * 3 + kw) * 16 + (ch * 4 + cig)) * COUT + co_base + l16)) * 8;
        short8 a0 = *reinterpret_cast<const short8*>(wp);
        short8 a1 = *reinterpret_cast<const short8*>(wp + 16 * 8);
        // B fragments: shifted LDS reads (kw taps share staged rows)
        short8 b[4];
        #pragma unroll
        for (int nr = 0; nr < 4; ++nr)
          b[nr] = *reinterpret_cast<const short8*>(&xs[bbase + (nr * 16 + kw) * CSTR]);
        #pragma unroll
        for (int nr = 0; nr < 4; ++nr) {
          acc[0][nr] = __builtin_amdgcn_mfma_f32_16x16x32_bf16(a0, b[nr], acc[0][nr], 0, 0, 0);
          acc[1][nr] = __builtin_amdgcn_mfma_f32_16x16x32_bf16(a1, b[nr], acc[1][nr], 0, 0, 0);
        }
      }
    }
  }

  // ---- epilogue: C/D layout col=lane&15, row=(lane>>4)*4+reg ----
  const int rowd = cig * 4;
  #pragma unroll
  for (int m = 0; m < 2; ++m) {
    #pragma unroll
    for (int reg = 0; reg < 4; ++reg) {
      int co = co_base + m * 16 + rowd + reg;
      float bv = bias[co];
      float* op = out + (((size_t)n * COUT + co) * OH + oh) * OW;
      #pragma unroll
      for (int nr = 0; nr < 4; ++nr) {
        int ow = nr * 16 + l16;
        if (ow < OW) op[ow] = acc[m][nr][reg] + bv;
      }
    }
  }
}

extern "C" void kernel_launch(void* const* d_in, const int* in_sizes, int n_in,
                              void* d_out, int out_size, void* d_ws, size_t ws_size,
                              hipStream_t stream) {
  (void)in_sizes; (void)n_in; (void)out_size; (void)ws_size;
  const float* x    = (const float*)d_in[0];
  const float* w    = (const float*)d_in[1];
  const float* bias = (const float*)d_in[2];
  float* out = (float*)d_out;
  unsigned short* w2 = (unsigned short*)d_ws;   // 589,824 B

  repack_w<<<dim3((COUT * CIN * 9 + 255) / 256), dim3(256), 0, stream>>>(w, w2);
  conv_mfma<<<dim3(27, 4, 32), dim3(256), 0, stream>>>(x, w2, bias, out);
}

// Round 2
// 127.278 us; speedup vs baseline: 1.3241x; 1.3241x over previous
//
#include <hip/hip_runtime.h>
#include <hip/hip_bf16.h>

#define CIN 128
#define COUT 256
#define H 56
#define W 56
#define OH 54
#define OW 54

#define CSTR 136   // LDS ci stride (bf16 elems): 272B -> odd 16B-granule stride
#define IWP 66     // iw dim incl. zero pad so (nr*16+15+kw) reads stay in-bounds

typedef __attribute__((ext_vector_type(8))) short short8;
typedef __attribute__((ext_vector_type(4))) float floatx4;

static __device__ __forceinline__ unsigned short f2bf(float f) {
  unsigned int u = __builtin_bit_cast(unsigned int, f);
  u += 0x7fffu + ((u >> 16) & 1u);   // RNE
  return (unsigned short)(u >> 16);
}

// w[co][ci][kh][kw] f32  ->  w2[kh][kw][c8][co][j] bf16   (ci = c8*8 + j)
__global__ void repack_w(const float* __restrict__ w, unsigned short* __restrict__ w2) {
  int idx = blockIdx.x * 256 + threadIdx.x;
  if (idx >= COUT * CIN * 9) return;
  int kw = idx % 3, t1 = idx / 3;
  int kh = t1 % 3, t2 = t1 / 3;
  int ci = t2 % CIN;
  int co = t2 / CIN;
  int c8 = ci >> 3, j = ci & 7;
  w2[((((kh * 3 + kw) * 16 + c8) * COUT + co) * 8) + j] = f2bf(w[idx]);
}

// Block: 512 threads = 8 waves = 4 co-groups(64 couts) x 2 output rows.
// Computes ALL 256 couts for one output row pair -> x staged once (not 4x).
__global__ __launch_bounds__(512, 4) void conv_mfma(
    const float* __restrict__ x, const unsigned short* __restrict__ w2,
    const float* __restrict__ bias, float* __restrict__ out) {
  __shared__ alignas(16) unsigned short xs[4 * IWP * CSTR];  // 71,808 B

  const int ohp = blockIdx.x;   // 0..26  (output row pair)
  const int n   = blockIdx.y;   // 0..31
  const int oh0 = ohp * 2;
  const int tid = threadIdx.x;

  // ---- zero the iw pad region [56,66) : 4 rows x 10 iw x 17 granules ----
  {
    short8 zz = {0, 0, 0, 0, 0, 0, 0, 0};
    for (int i = tid; i < 4 * 10 * 17; i += 512) {
      int r = i / 170, rem = i % 170;
      int iw = 56 + rem / 17, g = rem % 17;
      *reinterpret_cast<short8*>(&xs[(r * IWP + iw) * CSTR + g * 8]) = zz;
    }
  }

  // ---- stage x rows: f32 global -> bf16 LDS, transposed to [row][iw][ci] ----
  // slots: 4 rows x 16 c8 x 56 iw = 3584 = 7 * 512 (exact)
  for (int s = tid; s < 3584; s += 512) {
    int iw = s % 56;
    int t  = s / 56;          // 0..63
    int c8 = t & 15, r = t >> 4;
    const float* xp = x + (size_t)n * CIN * (H * W) + (oh0 + r) * W + iw;
    short8 v;
    #pragma unroll
    for (int j = 0; j < 8; ++j)
      v[j] = (short)f2bf(xp[(size_t)(c8 * 8 + j) * (H * W)]);
    *reinterpret_cast<short8*>(&xs[(r * IWP + iw) * CSTR + c8 * 8]) = v;
  }
  __syncthreads();

  // ---- wave decomposition: 8 waves = 4 co-groups x 2 output rows ----
  const int wid  = tid >> 6;
  const int lane = tid & 63;
  const int wm   = wid >> 1;       // co group (0..3) -> 64 couts
  const int wn   = wid & 1;        // which output row of the pair
  const int l16  = lane & 15;
  const int cig  = lane >> 4;      // 0..3

  const int co_base = wm * 64;
  const int oh = oh0 + wn;

  floatx4 acc[4][4];
  #pragma unroll
  for (int m = 0; m < 4; ++m)
    #pragma unroll
    for (int nr = 0; nr < 4; ++nr)
      acc[m][nr] = (floatx4){0.f, 0.f, 0.f, 0.f};

  for (int kh = 0; kh < 3; ++kh) {
    const int row = wn + kh;       // 0..3
    #pragma unroll
    for (int ch = 0; ch < 4; ++ch) {
      const int bbase = (row * IWP + l16) * CSTR + ch * 32 + cig * 8;
      #pragma unroll
      for (int kw = 0; kw < 3; ++kw) {
        // A fragments: direct from global (L1/L2-resident repacked weights)
        const unsigned short* wp =
            w2 + ((size_t)(((kh * 3 + kw) * 16 + (ch * 4 + cig)) * COUT + co_base + l16)) * 8;
        short8 a[4];
        #pragma unroll
        for (int m = 0; m < 4; ++m)
          a[m] = *reinterpret_cast<const short8*>(wp + m * 16 * 8);
        // B fragments: shifted LDS reads (kw taps share staged rows)
        short8 b[4];
        #pragma unroll
        for (int nr = 0; nr < 4; ++nr)
          b[nr] = *reinterpret_cast<const short8*>(&xs[bbase + (nr * 16 + kw) * CSTR]);
        #pragma unroll
        for (int m = 0; m < 4; ++m)
          #pragma unroll
          for (int nr = 0; nr < 4; ++nr)
            acc[m][nr] = __builtin_amdgcn_mfma_f32_16x16x32_bf16(a[m], b[nr], acc[m][nr], 0, 0, 0);
      }
    }
  }

  // ---- epilogue: C/D layout col=lane&15, row=(lane>>4)*4+reg ----
  const int rowd = cig * 4;
  #pragma unroll
  for (int m = 0; m < 4; ++m) {
    #pragma unroll
    for (int reg = 0; reg < 4; ++reg) {
      int co = co_base + m * 16 + rowd + reg;
      float bv = bias[co];
      float* op = out + (((size_t)n * COUT + co) * OH + oh) * OW;
      #pragma unroll
      for (int nr = 0; nr < 4; ++nr) {
        int ow = nr * 16 + l16;
        if (ow < OW) op[ow] = acc[m][nr][reg] + bv;
      }
    }
  }
}

extern "C" void kernel_launch(void* const* d_in, const int* in_sizes, int n_in,
                              void* d_out, int out_size, void* d_ws, size_t ws_size,
                              hipStream_t stream) {
  (void)in_sizes; (void)n_in; (void)out_size; (void)ws_size;
  const float* x    = (const float*)d_in[0];
  const float* w    = (const float*)d_in[1];
  const float* bias = (const float*)d_in[2];
  float* out = (float*)d_out;
  unsigned short* w2 = (unsigned short*)d_ws;   // 589,824 B

  repack_w<<<dim3((COUT * CIN * 9 + 255) / 256), dim3(256), 0, stream>>>(w, w2);
  conv_mfma<<<dim3(27, 32), dim3(512), 0, stream>>>(x, w2, bias, out);
}

// Round 3
// 98.483 us; speedup vs baseline: 1.7113x; 1.2924x over previous
//
#include <hip/hip_runtime.h>
#include <hip/hip_bf16.h>

#define CIN 128
#define COUT 256
#define H 56
#define W 56
#define OH 54
#define OW 54

typedef __attribute__((ext_vector_type(8))) short short8;
typedef __attribute__((ext_vector_type(4))) float floatx4;

typedef __attribute__((address_space(3))) unsigned int  lds_u32;
typedef const __attribute__((address_space(1))) unsigned int glb_u32;

static __device__ __forceinline__ unsigned short f2bf(float f) {
  unsigned int u = __builtin_bit_cast(unsigned int, f);
  u += 0x7fffu + ((u >> 16) & 1u);   // RNE
  return (unsigned short)(u >> 16);
}

// ---------- prepass 1: w[co][ci][kh][kw] f32 -> w2[k16][co][8] bf16 ----------
// k16 = (kh*3+kw)*16 + c8 ; ci = c8*8 + j
__global__ void repack_w(const float* __restrict__ w, unsigned short* __restrict__ w2) {
  int idx = blockIdx.x * 256 + threadIdx.x;
  if (idx >= COUT * CIN * 9) return;
  int kw = idx % 3, t1 = idx / 3;
  int kh = t1 % 3, t2 = t1 / 3;
  int ci = t2 % CIN;
  int co = t2 / CIN;
  int c8 = ci >> 3, j = ci & 7;
  w2[((((kh * 3 + kw) * 16 + c8) * COUT + co) * 8) + j] = f2bf(w[idx]);
}

// ---------- prepass 2: x NCHW f32 -> xb[n][h][g'] bf16, g' = iw*16 + (c16 ^ (iw&7)) ----
// 16B granule (8 ci) per (iw,c16); swizzle pre-applied so LDS stays linear (rule #21).
__global__ void repack_x(const float* __restrict__ x, unsigned short* __restrict__ xb) {
  int t = blockIdx.x * 256 + threadIdx.x;   // 32*56*16*56 = 1,605,632 = 6272*256
  int iw = t % 56, t1 = t / 56;
  int c16 = t1 & 15, t2 = t1 >> 4;
  int h = t2 % 56, n = t2 / 56;
  const float* xp = x + (((size_t)n * CIN + c16 * 8) * H + h) * W + iw;
  short8 v;
  #pragma unroll
  for (int j = 0; j < 8; ++j)
    v[j] = (short)f2bf(xp[(size_t)j * (H * W)]);
  int gp = iw * 16 + (c16 ^ (iw & 7));
  *reinterpret_cast<short8*>(&xb[(((size_t)n * H + h) * 896 + gp) * 8]) = v;
}

// ---------- main conv: 8 waves = 4 co-groups x 2 rows; wave = 64co x 64px ----------
__global__ __launch_bounds__(512, 4) void conv2(
    const unsigned short* __restrict__ xb, const unsigned short* __restrict__ w2,
    const float* __restrict__ bias, float* __restrict__ out) {
  // 4 rows x 896 granules + 160-granule overrun pad (garbage px>=54 reads) = 59,904 B
  __shared__ alignas(16) unsigned short xs[3744 * 8];

  // XCD-bijective swizzle: 864 % 8 == 0
  const int f = blockIdx.x;
  const int swz = (f & 7) * 108 + (f >> 3);
  const int ohp = swz % 27;
  const int n   = swz / 27;
  const int oh0 = ohp * 2;
  const int tid = threadIdx.x;
  const int wid  = tid >> 6;
  const int lane = tid & 63;

  // ---- stage 4 contiguous rows (3584 granules) via global_load_lds, 7 per thread ----
  {
    const unsigned short* src = xb + ((size_t)n * H + oh0) * 896 * 8;
    #pragma unroll
    for (int i = 0; i < 7; ++i) {
      int idx = (wid * 7 + i) * 64;                 // wave-uniform granule base
      __builtin_amdgcn_global_load_lds(
          (glb_u32*)(src + (size_t)(idx + lane) * 8),
          (lds_u32*)(&xs[idx * 8]), 16, 0, 0);
    }
  }
  asm volatile("s_waitcnt vmcnt(0)" ::: "memory");
  __syncthreads();

  const int wm   = wid >> 1;       // co group (0..3) -> 64 couts
  const int wn   = wid & 1;        // output row within the pair
  const int l16  = lane & 15;
  const int cig  = lane >> 4;      // 0..3

  const int co_base = wm * 64;
  const int oh = oh0 + wn;

  floatx4 acc[4][4];
  #pragma unroll
  for (int m = 0; m < 4; ++m)
    #pragma unroll
    for (int nr = 0; nr < 4; ++nr)
      acc[m][nr] = (floatx4){0.f, 0.f, 0.f, 0.f};

  #pragma unroll
  for (int kh = 0; kh < 3; ++kh) {
    const int row = wn + kh;       // 0..3
    #pragma unroll
    for (int ch = 0; ch < 4; ++ch) {
      #pragma unroll
      for (int kw = 0; kw < 3; ++kw) {
        // A fragments: direct global (L1/L2-resident repacked weights)
        const unsigned short* wp =
            w2 + ((size_t)(((kh * 3 + kw) * 16 + (ch * 4 + cig)) * COUT + co_base + l16)) * 8;
        short8 a[4];
        #pragma unroll
        for (int m = 0; m < 4; ++m)
          a[m] = *reinterpret_cast<const short8*>(wp + m * 16 * 8);
        // B fragments: swizzled LDS reads (8 lanes/bank-group = b128 minimum)
        const int iwl = l16 + kw;
        const int c16x = (ch * 4 + cig) ^ (iwl & 7);
        const int boff = (row * 896 + iwl * 16 + c16x) * 8;   // ushort index
        short8 b[4];
        #pragma unroll
        for (int nr = 0; nr < 4; ++nr)
          b[nr] = *reinterpret_cast<const short8*>(&xs[boff + nr * 16 * 16 * 8]);
        #pragma unroll
        for (int m = 0; m < 4; ++m)
          #pragma unroll
          for (int nr = 0; nr < 4; ++nr)
            acc[m][nr] = __builtin_amdgcn_mfma_f32_16x16x32_bf16(a[m], b[nr], acc[m][nr], 0, 0, 0);
      }
    }
  }

  // ---- epilogue: C/D layout col=lane&15, row=(lane>>4)*4+reg ----
  const int rowd = cig * 4;
  #pragma unroll
  for (int m = 0; m < 4; ++m) {
    #pragma unroll
    for (int reg = 0; reg < 4; ++reg) {
      int co = co_base + m * 16 + rowd + reg;
      float bv = bias[co];
      float* op = out + (((size_t)n * COUT + co) * OH + oh) * OW;
      #pragma unroll
      for (int nr = 0; nr < 4; ++nr) {
        int ow = nr * 16 + l16;
        if (ow < OW) op[ow] = acc[m][nr][reg] + bv;
      }
    }
  }
}

// ================== fallback path (ws too small): round-2 kernel ==================
#define CSTR 136
#define IWP 66

__global__ __launch_bounds__(512, 4) void conv_fb(
    const float* __restrict__ x, const unsigned short* __restrict__ w2,
    const float* __restrict__ bias, float* __restrict__ out) {
  __shared__ alignas(16) unsigned short xsf[4 * IWP * CSTR];

  const int ohp = blockIdx.x;
  const int n   = blockIdx.y;
  const int oh0 = ohp * 2;
  const int tid = threadIdx.x;

  {
    short8 zz = {0, 0, 0, 0, 0, 0, 0, 0};
    for (int i = tid; i < 4 * 10 * 17; i += 512) {
      int r = i / 170, rem = i % 170;
      int iw = 56 + rem / 17, g = rem % 17;
      *reinterpret_cast<short8*>(&xsf[(r * IWP + iw) * CSTR + g * 8]) = zz;
    }
  }
  for (int s = tid; s < 3584; s += 512) {
    int iw = s % 56;
    int t  = s / 56;
    int c8 = t & 15, r = t >> 4;
    const float* xp = x + (size_t)n * CIN * (H * W) + (oh0 + r) * W + iw;
    short8 v;
    #pragma unroll
    for (int j = 0; j < 8; ++j)
      v[j] = (short)f2bf(xp[(size_t)(c8 * 8 + j) * (H * W)]);
    *reinterpret_cast<short8*>(&xsf[(r * IWP + iw) * CSTR + c8 * 8]) = v;
  }
  __syncthreads();

  const int wid  = tid >> 6;
  const int lane = tid & 63;
  const int wm   = wid >> 1;
  const int wn   = wid & 1;
  const int l16  = lane & 15;
  const int cig  = lane >> 4;

  const int co_base = wm * 64;
  const int oh = oh0 + wn;

  floatx4 acc[4][4];
  #pragma unroll
  for (int m = 0; m < 4; ++m)
    #pragma unroll
    for (int nr = 0; nr < 4; ++nr)
      acc[m][nr] = (floatx4){0.f, 0.f, 0.f, 0.f};

  for (int kh = 0; kh < 3; ++kh) {
    const int row = wn + kh;
    #pragma unroll
    for (int ch = 0; ch < 4; ++ch) {
      const int bbase = (row * IWP + l16) * CSTR + ch * 32 + cig * 8;
      #pragma unroll
      for (int kw = 0; kw < 3; ++kw) {
        const unsigned short* wp =
            w2 + ((size_t)(((kh * 3 + kw) * 16 + (ch * 4 + cig)) * COUT + co_base + l16)) * 8;
        short8 a[4];
        #pragma unroll
        for (int m = 0; m < 4; ++m)
          a[m] = *reinterpret_cast<const short8*>(wp + m * 16 * 8);
        short8 b[4];
        #pragma unroll
        for (int nr = 0; nr < 4; ++nr)
          b[nr] = *reinterpret_cast<const short8*>(&xsf[bbase + (nr * 16 + kw) * CSTR]);
        #pragma unroll
        for (int m = 0; m < 4; ++m)
          #pragma unroll
          for (int nr = 0; nr < 4; ++nr)
            acc[m][nr] = __builtin_amdgcn_mfma_f32_16x16x32_bf16(a[m], b[nr], acc[m][nr], 0, 0, 0);
      }
    }
  }

  const int rowd = cig * 4;
  #pragma unroll
  for (int m = 0; m < 4; ++m) {
    #pragma unroll
    for (int reg = 0; reg < 4; ++reg) {
      int co = co_base + m * 16 + rowd + reg;
      float bv = bias[co];
      float* op = out + (((size_t)n * COUT + co) * OH + oh) * OW;
      #pragma unroll
      for (int nr = 0; nr < 4; ++nr) {
        int ow = nr * 16 + l16;
        if (ow < OW) op[ow] = acc[m][nr][reg] + bv;
      }
    }
  }
}

extern "C" void kernel_launch(void* const* d_in, const int* in_sizes, int n_in,
                              void* d_out, int out_size, void* d_ws, size_t ws_size,
                              hipStream_t stream) {
  (void)in_sizes; (void)n_in; (void)out_size;
  const float* x    = (const float*)d_in[0];
  const float* w    = (const float*)d_in[1];
  const float* bias = (const float*)d_in[2];
  float* out = (float*)d_out;

  const size_t W2_BYTES = (size_t)9 * 16 * COUT * 8 * 2;            // 589,824
  const size_t XB_BYTES = (size_t)32 * H * 896 * 8 * 2;             // 25,690,112
  unsigned short* w2 = (unsigned short*)d_ws;

  repack_w<<<dim3((COUT * CIN * 9 + 255) / 256), dim3(256), 0, stream>>>(w, w2);

  if (ws_size >= W2_BYTES + XB_BYTES) {
    unsigned short* xb = (unsigned short*)((char*)d_ws + W2_BYTES);
    repack_x<<<dim3(6272), dim3(256), 0, stream>>>(x, xb);
    conv2<<<dim3(864), dim3(512), 0, stream>>>(xb, w2, bias, out);
  } else {
    conv_fb<<<dim3(27, 32), dim3(512), 0, stream>>>(x, w2, bias, out);
  }
}